// Round 1
// baseline (643.268 us; speedup 1.0000x reference)
//
#include <hip/hip_runtime.h>

// LeNet C3 masked conv, overwrite semantics: each output channel j is produced
// solely by the LAST input channel h with MASK[h][j]==1, with filter
// weights[h][pos] where pos = index of j within IDX[h]. Channels 0,1 of x are
// dead. Tables below encode the winners.
//
// x:       [B, 6, 14, 14] f32   (only ch 2..5 read; contiguous 784 f per batch)
// weights: [6, 10, 5, 5]  f32   -> filter offset (h*10+pos)*25
// bias:    [16]           f32
// out:     [B, 16, 10, 10] f32

#define NB 8        // batches per block
#define THREADS 256 // 8 batches x 16 j x 2 row-halves

__device__ __constant__ int C3_H[16]    = {2,3,4,5,5,5,3,4,5,5,5,5,4,5,5,5};
__device__ __constant__ int C3_WIDX[16] = {20,30,40,50,51,52,33,43,53,54,55,56,47,57,58,59};

__global__ __launch_bounds__(THREADS, 3)
void c3_kernel(const float* __restrict__ x,
               const float* __restrict__ w,
               const float* __restrict__ bias,
               float* __restrict__ out) {
    // Output staging so the final global store is fully linear float4.
    __shared__ float so[NB * 1600];

    const int t    = threadIdx.x;
    const int half = t & 1;         // which 5 output rows
    const int j    = (t >> 1) & 15; // output channel
    const int bloc = t >> 5;        // batch within block (0..7) -> only 2 blocs
                                    // per wave (limits LDS staging conflicts to 4-way)
    const long long b = (long long)blockIdx.x * NB + bloc;

    const int   h  = C3_H[j];
    const float bj = bias[j];

    // Filter -> registers (25 scalar loads, L2-resident after first block).
    const float* __restrict__ wp = w + C3_WIDX[j] * 25;
    float wr[25];
#pragma unroll
    for (int i = 0; i < 25; ++i) wr[i] = wp[i];

    // This thread's input channel plane [14][14], rows r0 .. r0+8 needed.
    const float* __restrict__ xp = x + b * 1176 + h * 196;
    const int r0 = half * 5;

    // 5-row x 14-col register sliding window; rows loaded as 7x float2
    // (row starts are 8B-aligned: 14*r floats).
    float xw[5][14];
#pragma unroll
    for (int r = 0; r < 4; ++r) {
        const float2* rp = (const float2*)(xp + (r0 + r) * 14);
#pragma unroll
        for (int i = 0; i < 7; ++i) {
            float2 v = rp[i];
            xw[r][2 * i] = v.x;
            xw[r][2 * i + 1] = v.y;
        }
    }

    float* sbase = &so[bloc * 1600 + j * 100 + r0 * 10];

#pragma unroll
    for (int orow = 0; orow < 5; ++orow) {
        // Load x row r0+orow+4 into the rotating slot (indices fold at compile
        // time under full unroll -> pure register renaming, no scratch).
        {
            const float2* rp = (const float2*)(xp + (r0 + orow + 4) * 14);
            float* d = xw[(orow + 4) % 5];
#pragma unroll
            for (int i = 0; i < 7; ++i) {
                float2 v = rp[i];
                d[2 * i] = v.x;
                d[2 * i + 1] = v.y;
            }
        }

        float acc[10];
#pragma unroll
        for (int c = 0; c < 10; ++c) acc[c] = bj;

#pragma unroll
        for (int u = 0; u < 5; ++u) {
            const float* row = xw[(orow + u) % 5];
#pragma unroll
            for (int v = 0; v < 5; ++v) {
                const float wv = wr[u * 5 + v];
#pragma unroll
                for (int c = 0; c < 10; ++c)
                    acc[c] = fmaf(wv, row[c + v], acc[c]);
            }
        }

        // Stage one output row (10 floats) as 5x ds_write_b64.
        float2* sp = (float2*)(sbase + orow * 10);
#pragma unroll
        for (int i = 0; i < 5; ++i) sp[i] = make_float2(acc[2 * i], acc[2 * i + 1]);
    }

    __syncthreads();

    // Coalesced linear copy-out: block's 8 batches are contiguous in out.
    const float4* __restrict__ src = (const float4*)so;
    float4* __restrict__ dst = (float4*)(out + (size_t)blockIdx.x * (NB * 1600));
    constexpr int NQ = NB * 1600 / 4; // 3200 float4 per block
#pragma unroll
    for (int i = 0; i < (NQ + THREADS - 1) / THREADS; ++i) {
        int idx = t + i * THREADS;
        if (idx < NQ) dst[idx] = src[idx];
    }
}

extern "C" void kernel_launch(void* const* d_in, const int* in_sizes, int n_in,
                              void* d_out, int out_size, void* d_ws, size_t ws_size,
                              hipStream_t stream) {
    const float* x    = (const float*)d_in[0];
    const float* w    = (const float*)d_in[1];
    const float* bias = (const float*)d_in[2];
    float* out        = (float*)d_out;

    const int B = in_sizes[0] / (6 * 14 * 14); // 65536
    const int nblocks = B / NB;                // 8192

    hipLaunchKernelGGL(c3_kernel, dim3(nblocks), dim3(THREADS), 0, stream,
                       x, w, bias, out);
}

// Round 2
// 618.211 us; speedup vs baseline: 1.0405x; 1.0405x over previous
//
#include <hip/hip_runtime.h>

// LeNet C3 masked conv, overwrite semantics: each output channel j is produced
// solely by the LAST input channel h with MASK[h][j]==1 (filter offset
// (h*10+pos)*25). Input channels 0,1 are dead.
//
// x:       [B, 6, 14, 14] f32   (only ch 2..5 read; used region per batch is
//                                the contiguous float range [392, 1176))
// weights: [6, 10, 5, 5]  f32
// bias:    [16]           f32
// out:     [B, 16, 10, 10] f32
//
// R1 change vs R0: x is now cooperatively staged into LDS with linear float4
// global loads (R0's per-lane scattered window loads were VMEM-transaction
// bound: ~16 L1 transactions per wave load). Window reads now hit LDS where
// same-(h,half) lanes broadcast.

#define NB 8        // batches per block
#define THREADS 256 // 8 batches x 16 j x 2 row-halves
#define XPITCH 788  // per-batch pitch in LDS floats (784 + 4 pad; 788*4 % 16 == 0)

__device__ __constant__ int C3_HREL[16] = {0,1,2,3,3,3,1,2,3,3,3,3,2,3,3,3}; // h-2
__device__ __constant__ int C3_WIDX[16] = {20,30,40,50,51,52,33,43,53,54,55,56,47,57,58,59};

__global__ __launch_bounds__(THREADS, 2)
void c3_kernel(const float* __restrict__ x,
               const float* __restrict__ w,
               const float* __restrict__ bias,
               float* __restrict__ out) {
    __shared__ float sx[NB * XPITCH];  // staged input planes (ch2..5), 25.2 KB
    __shared__ float so[NB * 1600];    // staged output tile, 51.2 KB

    const int t = threadIdx.x;

    // ---- Stage x: 8 batches x 196 float4 (contiguous 784-float segment per
    // batch starting at float 392 of the 1176-float batch record). ----
    {
        const float4* __restrict__ x4 = (const float4*)x;
        const long long base = (long long)blockIdx.x * NB;
#pragma unroll
        for (int i = 0; i < (NB * 196 + THREADS - 1) / THREADS; ++i) {
            int idx = t + i * THREADS;
            if (idx < NB * 196) {
                int bat = idx / 196;       // magic-mul
                int q   = idx - bat * 196;
                float4 v = x4[(base + bat) * 294 + 98 + q];
                *(float4*)&sx[bat * XPITCH + q * 4] = v;
            }
        }
    }

    const int half = t & 1;         // which 5 output rows
    const int j    = (t >> 1) & 15; // output channel
    const int bloc = t >> 5;        // batch within block

    const int   hrel = C3_HREL[j];
    const float bj   = bias[j];

    // Filter -> registers (same address across the 4 lanes sharing j -> L2/L1).
    const float* __restrict__ wp = w + C3_WIDX[j] * 25;
    float wr[25];
#pragma unroll
    for (int i = 0; i < 25; ++i) wr[i] = wp[i];

    __syncthreads();

    const float* __restrict__ xp = &sx[bloc * XPITCH + hrel * 196];
    const int r0 = half * 5;

    // 5-row x 14-col register sliding window, fed from LDS (b64 reads,
    // <=16 distinct addrs/wave, <=2 per bank pair -> conflict-free).
    float xw[5][14];
#pragma unroll
    for (int r = 0; r < 4; ++r) {
        const float2* rp = (const float2*)(xp + (r0 + r) * 14);
#pragma unroll
        for (int i = 0; i < 7; ++i) {
            float2 v = rp[i];
            xw[r][2 * i] = v.x;
            xw[r][2 * i + 1] = v.y;
        }
    }

    float* sbase = &so[bloc * 1600 + j * 100 + r0 * 10];

#pragma unroll
    for (int orow = 0; orow < 5; ++orow) {
        {
            const float2* rp = (const float2*)(xp + (r0 + orow + 4) * 14);
            float* d = xw[(orow + 4) % 5];
#pragma unroll
            for (int i = 0; i < 7; ++i) {
                float2 v = rp[i];
                d[2 * i] = v.x;
                d[2 * i + 1] = v.y;
            }
        }

        float acc[10];
#pragma unroll
        for (int c = 0; c < 10; ++c) acc[c] = bj;

#pragma unroll
        for (int u = 0; u < 5; ++u) {
            const float* row = xw[(orow + u) % 5];
#pragma unroll
            for (int v = 0; v < 5; ++v) {
                const float wv = wr[u * 5 + v];
#pragma unroll
                for (int c = 0; c < 10; ++c)
                    acc[c] = fmaf(wv, row[c + v], acc[c]);
            }
        }

        // Stage one output row (10 floats) as 5x ds_write_b64.
        float2* sp = (float2*)(sbase + orow * 10);
#pragma unroll
        for (int i = 0; i < 5; ++i) sp[i] = make_float2(acc[2 * i], acc[2 * i + 1]);
    }

    __syncthreads();

    // Coalesced linear copy-out: block's 8 batches are contiguous in out.
    const float4* __restrict__ src = (const float4*)so;
    float4* __restrict__ dst = (float4*)(out + (size_t)blockIdx.x * (NB * 1600));
    constexpr int NQ = NB * 1600 / 4; // 3200 float4 per block
#pragma unroll
    for (int i = 0; i < (NQ + THREADS - 1) / THREADS; ++i) {
        int idx = t + i * THREADS;
        if (idx < NQ) dst[idx] = src[idx];
    }
}

extern "C" void kernel_launch(void* const* d_in, const int* in_sizes, int n_in,
                              void* d_out, int out_size, void* d_ws, size_t ws_size,
                              hipStream_t stream) {
    const float* x    = (const float*)d_in[0];
    const float* w    = (const float*)d_in[1];
    const float* bias = (const float*)d_in[2];
    float* out        = (float*)d_out;

    const int B = in_sizes[0] / (6 * 14 * 14); // 65536
    const int nblocks = B / NB;                // 8192

    hipLaunchKernelGGL(c3_kernel, dim3(nblocks), dim3(THREADS), 0, stream,
                       x, w, bias, out);
}